// Round 3
// baseline (333.882 us; speedup 1.0000x reference)
//
#include <hip/hip_runtime.h>
#include <hip/hip_bf16.h>

#define B_ROWS 32768
#define L_DIM 512
#define H_DIM 1024
#define E_DIM 128
#define K_EXP 8
#define NBLK 128          // sort blocks: 32768/256
#define MAXT 264          // max padded 128-row tiles (256 + 8)
#define MAXB (MAXT * 128) // 33792

typedef __bf16 bf16x8 __attribute__((ext_vector_type(8)));
typedef float f32x4 __attribute__((ext_vector_type(4)));

__device__ __forceinline__ void gload16(const void* src, void* dst) {
    __builtin_amdgcn_global_load_lds(
        (const __attribute__((address_space(1))) unsigned int*)src,
        (__attribute__((address_space(3))) unsigned int*)dst, 16, 0, 0);
}

// meta layout: [0]=nTiles  [1..9]=seg[9]  [10..18]=segP[9]  [19..26]=cnt[8]  [27..27+MAXT)=tileExp
#define M_NT 0
#define M_SEG 1
#define M_SEGP 10
#define M_CNT 19
#define M_TEXP 27

// ---------------- sort: ids + per-block histogram ----------------
__global__ void k_ids_hist(const float* __restrict__ x, int* __restrict__ ids,
                           int* __restrict__ hist) {
    __shared__ int lh[K_EXP];
    int t = threadIdx.x;
    if (t < K_EXP) lh[t] = 0;
    __syncthreads();
    int i = blockIdx.x * 256 + t;
    int id = (int)x[(size_t)i * (L_DIM + 1) + L_DIM];
    ids[i] = id;
    atomicAdd(&lh[id], 1);
    __syncthreads();
    if (t < K_EXP) hist[blockIdx.x * K_EXP + t] = lh[t];
}

// ---------------- scan: padded segments, tile->expert map, block bases ----------------
__global__ void k_scan(const int* __restrict__ hist, int* __restrict__ base,
                       int* __restrict__ meta, int* __restrict__ order_pad) {
    __shared__ int c[K_EXP];
    __shared__ int sp[K_EXP + 1];
    __shared__ int scnt[K_EXP];
    int k = threadIdx.x;  // 64 threads
    if (k < K_EXP) {
        int run = 0;
        for (int b = 0; b < NBLK; ++b) {
            base[b * K_EXP + k] = run;
            run += hist[b * K_EXP + k];
        }
        c[k] = run;
    }
    __syncthreads();
    if (k == 0) {
        int s = 0, p = 0;
        for (int e = 0; e < K_EXP; ++e) {
            meta[M_SEG + e] = s;
            meta[M_SEGP + e] = p;
            meta[M_CNT + e] = c[e];
            sp[e] = p;
            scnt[e] = c[e];
            s += c[e];
            p += ((c[e] + 127) >> 7) << 7;
        }
        meta[M_SEG + K_EXP] = s;
        meta[M_SEGP + K_EXP] = p;
        sp[K_EXP] = p;
        int nT = p >> 7;
        meta[M_NT] = nT;
        for (int e = 0; e < K_EXP; ++e)
            for (int t2 = sp[e] >> 7; t2 < sp[e + 1] >> 7; ++t2)
                meta[M_TEXP + t2] = e;
        for (int t2 = nT; t2 < MAXT; ++t2) meta[M_TEXP + t2] = 0;
    }
    __syncthreads();
    if (k < K_EXP) {
        int s0 = sp[k];
        for (int b = 0; b < NBLK; ++b) base[b * K_EXP + k] += s0;
    }
    // init padded-tail slots of order_pad to a valid row (0)
    for (int e = 0; e < K_EXP; ++e) {
        int st = sp[e] + scnt[e], en = sp[e + 1];
        for (int p2 = st + k; p2 < en; p2 += 64) order_pad[p2] = 0;
    }
    for (int p2 = sp[K_EXP] + k; p2 < MAXB; p2 += 64) order_pad[p2] = 0;
}

// ---------------- stable order within block ----------------
__global__ void k_order(const int* __restrict__ ids, const int* __restrict__ base,
                        int* __restrict__ order) {
    __shared__ int sid[256];
    int t = threadIdx.x;
    int i = blockIdx.x * 256 + t;
    int my = ids[i];
    sid[t] = my;
    __syncthreads();
    int rank = 0;
    for (int j = 0; j < t; ++j) rank += (sid[j] == my) ? 1 : 0;
    order[base[blockIdx.x * K_EXP + my] + rank] = i;
}

// ---------------- gather sorted (padded) rows into packed bf16 xs ----------------
__global__ void k_gather(const float* __restrict__ x, const int* __restrict__ order,
                         __hip_bfloat16* __restrict__ xs) {
    int idx = blockIdx.x * 256 + threadIdx.x;
    int p = idx >> 7;            // 128 groups of 4 per row
    int c4 = (idx & 127) << 2;
    int src = order[p];
    const float* sp = x + (size_t)src * (L_DIM + 1) + c4;
    __hip_bfloat16 v[4];
    v[0] = __float2bfloat16(sp[0]);
    v[1] = __float2bfloat16(sp[1]);
    v[2] = __float2bfloat16(sp[2]);
    v[3] = __float2bfloat16(sp[3]);
    *(uint2*)(xs + (size_t)p * L_DIM + c4) = *(uint2*)v;
}

// ---------------- weight transpose + fp32->bf16:  W[K][N] -> Wt[N][K] ----------------
__global__ void k_transpose(const float* __restrict__ W, __hip_bfloat16* __restrict__ Wt,
                            int KDim, int NDim) {
    __shared__ float tile[32][33];
    int k0 = blockIdx.x << 5, n0 = blockIdx.y << 5;
    const float* Wb = W + (size_t)blockIdx.z * KDim * NDim;
    __hip_bfloat16* Wtb = Wt + (size_t)blockIdx.z * KDim * NDim;
    int tx = threadIdx.x & 31, ty = threadIdx.x >> 5;
    for (int i = ty; i < 32; i += 8)
        tile[i][tx] = Wb[(size_t)(k0 + i) * NDim + n0 + tx];
    __syncthreads();
    for (int i = ty; i < 32; i += 8)
        Wtb[(size_t)(n0 + i) * KDim + k0 + tx] = __float2bfloat16(tile[tx][i]);
}

// ---------------- fused encoder: z = leaky(leaky(xs@We1+be1)@We2+be2) ----------------
// One block per 128 padded rows. 8 H-chunks of 128; per chunk: MFMA GEMM (K=512)
// into acch, bias+leaky+cvt into swizzled LDS, then z-accumulate (K=128) with
// B-fragments streamed from L2-resident Wt2. h never touches HBM.
__launch_bounds__(256, 1)
__global__ void k_enc(const __hip_bfloat16* __restrict__ xs,
                      const __hip_bfloat16* __restrict__ Wt1,
                      const __hip_bfloat16* __restrict__ Wt2,
                      const float* __restrict__ be1,
                      const float* __restrict__ be2,
                      __hip_bfloat16* __restrict__ zb,
                      const int* __restrict__ meta) {
    __shared__ __align__(16) __hip_bfloat16 smem[2 * 2 * 128 * 32];  // 32 KB staging
    __shared__ __align__(16) __hip_bfloat16 hlds[4 * 128 * 32];      // 32 KB h chunk
    const int mt = blockIdx.x;
    if (mt >= meta[M_NT]) return;
    const int m0 = mt << 7;
    const int t = threadIdx.x, w = t >> 6, l = t & 63;
    const int wm = w >> 1, wn = w & 1, g = l >> 4, li = l & 15;
    const int q0 = 2 * w, r0 = l >> 2, s0 = l & 3;

    auto stageA = [&](int buf, int kt) {
#pragma unroll
        for (int qi = 0; qi < 2; ++qi) {
            int q = q0 + qi, r = q * 16 + r0;
            int ksg = s0 ^ ((r >> 1) & 3);
            gload16(xs + (size_t)(m0 + r) * L_DIM + kt * 32 + ksg * 8,
                    &smem[(buf * 2 + 0) * 4096 + q * 512]);
        }
    };
    auto stageB = [&](int buf, int kt, int c) {
#pragma unroll
        for (int qi = 0; qi < 2; ++qi) {
            int q = q0 + qi, r = q * 16 + r0;
            int ksg = s0 ^ ((r >> 1) & 3);
            gload16(Wt1 + (size_t)(c * 128 + r) * L_DIM + kt * 32 + ksg * 8,
                    &smem[(buf * 2 + 1) * 4096 + q * 512]);
        }
    };

    f32x4 accz[4][4];
#pragma unroll
    for (int i = 0; i < 4; ++i)
#pragma unroll
        for (int j = 0; j < 4; ++j) accz[i][j] = (f32x4){0.f, 0.f, 0.f, 0.f};

    stageA(0, 0);
    stageB(0, 0, 0);
    for (int c = 0; c < 8; ++c) {
        f32x4 acch[4][4];
#pragma unroll
        for (int i = 0; i < 4; ++i)
#pragma unroll
            for (int j = 0; j < 4; ++j) acch[i][j] = (f32x4){0.f, 0.f, 0.f, 0.f};

        for (int kt = 0; kt < 16; ++kt) {
            int buf = kt & 1;
            __syncthreads();
            if (kt < 15) { stageA(buf ^ 1, kt + 1); stageB(buf ^ 1, kt + 1, c); }
            bf16x8 af[4], bfr[4];
#pragma unroll
            for (int fm = 0; fm < 4; ++fm) {
                int rr = wm * 64 + fm * 16 + li;
                int ss = g ^ ((rr >> 1) & 3);
                af[fm] = *(const bf16x8*)&smem[(buf * 2 + 0) * 4096 + rr * 32 + ss * 8];
            }
#pragma unroll
            for (int fn = 0; fn < 4; ++fn) {
                int cc = wn * 64 + fn * 16 + li;
                int ss = g ^ ((cc >> 1) & 3);
                bfr[fn] = *(const bf16x8*)&smem[(buf * 2 + 1) * 4096 + cc * 32 + ss * 8];
            }
#pragma unroll
            for (int fm = 0; fm < 4; ++fm)
#pragma unroll
                for (int fn = 0; fn < 4; ++fn)
                    acch[fm][fn] = __builtin_amdgcn_mfma_f32_16x16x32_bf16(
                        af[fm], bfr[fn], acch[fm][fn], 0, 0, 0);
        }
        __syncthreads();                                 // all smem reads done
        if (c < 7) { stageA(0, 0); stageB(0, 0, c + 1); }  // prestage next chunk kt=0

        // h chunk -> swizzled LDS (bias + leaky + bf16)
        float bv1[4];
#pragma unroll
        for (int fn = 0; fn < 4; ++fn) bv1[fn] = be1[c * 128 + wn * 64 + fn * 16 + li];
#pragma unroll
        for (int fm = 0; fm < 4; ++fm)
#pragma unroll
            for (int i = 0; i < 4; ++i) {
                int r = wm * 64 + fm * 16 + g * 4 + i;
                int swr = (r >> 1) & 3;
#pragma unroll
                for (int fn = 0; fn < 4; ++fn) {
                    int cc = wn * 64 + fn * 16 + li;
                    float v = acch[fm][fn][i] + bv1[fn];
                    v = v > 0.f ? v : 0.01f * v;
                    int kblk = cc >> 5, k32 = cc & 31;
                    hlds[kblk * 4096 + r * 32 + ((k32 >> 3) ^ swr) * 8 + (k32 & 7)] =
                        __float2bfloat16(v);
                }
            }
        __syncthreads();                                 // hlds ready

        // z-accumulate: K=128 chunk slice, B frags streamed from global (L2)
#pragma unroll
        for (int kk = 0; kk < 4; ++kk) {
            bf16x8 af2[4], bf2[4];
#pragma unroll
            for (int fm = 0; fm < 4; ++fm) {
                int rr = wm * 64 + fm * 16 + li;
                int ss = g ^ ((rr >> 1) & 3);
                af2[fm] = *(const bf16x8*)&hlds[kk * 4096 + rr * 32 + ss * 8];
            }
#pragma unroll
            for (int fn = 0; fn < 4; ++fn) {
                int n = wn * 64 + fn * 16 + li;
                bf2[fn] = *(const bf16x8*)(Wt2 + (size_t)n * H_DIM + c * 128 + kk * 32 + g * 8);
            }
#pragma unroll
            for (int fm = 0; fm < 4; ++fm)
#pragma unroll
                for (int fn = 0; fn < 4; ++fn)
                    accz[fm][fn] = __builtin_amdgcn_mfma_f32_16x16x32_bf16(
                        af2[fm], bf2[fn], accz[fm][fn], 0, 0, 0);
        }
    }

    // epilogue: z = leaky(accz + be2) -> zb (padded rows included)
    float bv2[4];
#pragma unroll
    for (int fn = 0; fn < 4; ++fn) bv2[fn] = be2[wn * 64 + fn * 16 + li];
#pragma unroll
    for (int fm = 0; fm < 4; ++fm)
#pragma unroll
        for (int i = 0; i < 4; ++i) {
            int r = m0 + wm * 64 + fm * 16 + g * 4 + i;
#pragma unroll
            for (int fn = 0; fn < 4; ++fn) {
                float v = accz[fm][fn][i] + bv2[fn];
                v = v > 0.f ? v : 0.01f * v;
                zb[(size_t)r * E_DIM + wn * 64 + fn * 16 + li] = __float2bfloat16(v);
            }
        }
}

// ---------------- decoder GEMMs (padded tiles, per-tile expert) ----------------
// C[M,N] = epi(A[M,KD] @ Bt[e][N,KD]^T + bias[e]); XCD-chunked block swizzle.
template <int KD, int ND, bool LEAKY, bool MAPROW>
__launch_bounds__(256)
__global__ void gemm_dec(const __hip_bfloat16* __restrict__ A,
                         const __hip_bfloat16* __restrict__ Bt,
                         const float* __restrict__ bias,
                         void* __restrict__ Cout,
                         const int* __restrict__ meta) {
    __shared__ __align__(16) __hip_bfloat16 smem[2 * 2 * 128 * 32];
    constexpr int NTN = ND / 128;
    constexpr int TOT = NTN * MAXT;   // divisible by 8 (MAXT=264)
    int id = blockIdx.x;
    int wg = (id & 7) * (TOT / 8) + (id >> 3);   // bijective XCD chunking
    int mt = wg / NTN, nt = wg % NTN;
    if (mt >= meta[M_NT]) return;
    const int e = meta[M_TEXP + mt];
    const int m0 = mt << 7, n0 = nt << 7;
    const __hip_bfloat16* Bp = Bt + (size_t)e * KD * ND;
    const float* bp = bias + (size_t)e * ND;

    const int t = threadIdx.x, w = t >> 6, l = t & 63;
    const int wm = w >> 1, wn = w & 1, g = l >> 4, li = l & 15;
    const int q0 = 2 * w, r0 = l >> 2, s0 = l & 3;

    f32x4 acc[4][4];
#pragma unroll
    for (int i = 0; i < 4; ++i)
#pragma unroll
        for (int j = 0; j < 4; ++j) acc[i][j] = (f32x4){0.f, 0.f, 0.f, 0.f};

    auto stage = [&](int buf, int kt) {
#pragma unroll
        for (int qi = 0; qi < 2; ++qi) {
            int q = q0 + qi, r = q * 16 + r0;
            int ksg = s0 ^ ((r >> 1) & 3);
            gload16(A + (size_t)(m0 + r) * KD + kt * 32 + ksg * 8,
                    &smem[(buf * 2 + 0) * 4096 + q * 512]);
        }
#pragma unroll
        for (int qi = 0; qi < 2; ++qi) {
            int q = q0 + qi, r = q * 16 + r0;
            int ksg = s0 ^ ((r >> 1) & 3);
            gload16(Bp + (size_t)(n0 + r) * KD + kt * 32 + ksg * 8,
                    &smem[(buf * 2 + 1) * 4096 + q * 512]);
        }
    };

    constexpr int NK = KD / 32;
    stage(0, 0);
    for (int kt = 0; kt < NK; ++kt) {
        int buf = kt & 1;
        __syncthreads();
        if (kt + 1 < NK) stage(buf ^ 1, kt + 1);
        bf16x8 af[4], bfr[4];
#pragma unroll
        for (int fm = 0; fm < 4; ++fm) {
            int rr = wm * 64 + fm * 16 + li;
            int ss = g ^ ((rr >> 1) & 3);
            af[fm] = *(const bf16x8*)&smem[(buf * 2 + 0) * 4096 + rr * 32 + ss * 8];
        }
#pragma unroll
        for (int fn = 0; fn < 4; ++fn) {
            int cc = wn * 64 + fn * 16 + li;
            int ss = g ^ ((cc >> 1) & 3);
            bfr[fn] = *(const bf16x8*)&smem[(buf * 2 + 1) * 4096 + cc * 32 + ss * 8];
        }
#pragma unroll
        for (int fm = 0; fm < 4; ++fm)
#pragma unroll
            for (int fn = 0; fn < 4; ++fn)
                acc[fm][fn] = __builtin_amdgcn_mfma_f32_16x16x32_bf16(
                    af[fm], bfr[fn], acc[fm][fn], 0, 0, 0);
    }

    float bv[4];
#pragma unroll
    for (int fn = 0; fn < 4; ++fn) bv[fn] = bp[n0 + wn * 64 + fn * 16 + li];
    int se = 0, sp2 = 0, ce = 0;
    if (MAPROW) { se = meta[M_SEG + e]; sp2 = meta[M_SEGP + e]; ce = meta[M_CNT + e]; }
#pragma unroll
    for (int fm = 0; fm < 4; ++fm)
#pragma unroll
        for (int i = 0; i < 4; ++i) {
            int rp = m0 + wm * 64 + fm * 16 + g * 4 + i;
#pragma unroll
            for (int fn = 0; fn < 4; ++fn) {
                float v = acc[fm][fn][i] + bv[fn];
                if (LEAKY) v = v > 0.f ? v : 0.01f * v;
                int col = n0 + wn * 64 + fn * 16 + li;
                if (MAPROW) {
                    int local = rp - sp2;
                    if (local < ce)
                        ((float*)Cout)[(size_t)(se + local) * ND + col] = v;
                } else {
                    ((__hip_bfloat16*)Cout)[(size_t)rp * ND + col] = __float2bfloat16(v);
                }
            }
        }
}

extern "C" void kernel_launch(void* const* d_in, const int* in_sizes, int n_in,
                              void* d_out, int out_size, void* d_ws, size_t ws_size,
                              hipStream_t stream) {
    (void)in_sizes; (void)n_in; (void)out_size; (void)ws_size;
    const float* x   = (const float*)d_in[0];
    const float* We1 = (const float*)d_in[1];
    const float* be1 = (const float*)d_in[2];
    const float* We2 = (const float*)d_in[3];
    const float* be2 = (const float*)d_in[4];
    const float* Wd1 = (const float*)d_in[5];
    const float* bd1 = (const float*)d_in[6];
    const float* Wd2 = (const float*)d_in[7];
    const float* bd2 = (const float*)d_in[8];
    float* out = (float*)d_out;

    char* w = (char*)d_ws;
    auto alloc = [&](size_t bytes) {
        char* p = w;
        w += (bytes + 255) & ~(size_t)255;
        return p;
    };
    int* ids       = (int*)alloc((size_t)B_ROWS * 4);
    int* order_pad = (int*)alloc((size_t)MAXB * 4);
    int* hist      = (int*)alloc((size_t)NBLK * K_EXP * 4);
    int* base      = (int*)alloc((size_t)NBLK * K_EXP * 4);
    int* meta      = (int*)alloc((size_t)(M_TEXP + MAXT) * 4);
    __hip_bfloat16* xs   = (__hip_bfloat16*)alloc((size_t)MAXB * L_DIM * 2);   // 34.6 MB
    __hip_bfloat16* zbuf = (__hip_bfloat16*)alloc((size_t)MAXB * E_DIM * 2);   // 8.7 MB
    __hip_bfloat16* hd   = (__hip_bfloat16*)alloc((size_t)MAXB * H_DIM * 2);   // 69.2 MB
    __hip_bfloat16* Wt1  = (__hip_bfloat16*)alloc((size_t)L_DIM * H_DIM * 2);
    __hip_bfloat16* Wt2  = (__hip_bfloat16*)alloc((size_t)H_DIM * E_DIM * 2);
    __hip_bfloat16* Wd1t = (__hip_bfloat16*)alloc((size_t)K_EXP * E_DIM * H_DIM * 2);
    __hip_bfloat16* Wd2t = (__hip_bfloat16*)alloc((size_t)K_EXP * H_DIM * L_DIM * 2);

    k_ids_hist<<<NBLK, 256, 0, stream>>>(x, ids, hist);
    k_scan<<<1, 64, 0, stream>>>(hist, base, meta, order_pad);
    k_order<<<NBLK, 256, 0, stream>>>(ids, base, order_pad);
    k_gather<<<(MAXB * (L_DIM / 4)) / 256, 256, 0, stream>>>(x, order_pad, xs);

    k_transpose<<<dim3(L_DIM / 32, H_DIM / 32, 1), 256, 0, stream>>>(We1, Wt1, L_DIM, H_DIM);
    k_transpose<<<dim3(H_DIM / 32, E_DIM / 32, 1), 256, 0, stream>>>(We2, Wt2, H_DIM, E_DIM);
    k_transpose<<<dim3(E_DIM / 32, H_DIM / 32, K_EXP), 256, 0, stream>>>(Wd1, Wd1t, E_DIM, H_DIM);
    k_transpose<<<dim3(H_DIM / 32, L_DIM / 32, K_EXP), 256, 0, stream>>>(Wd2, Wd2t, H_DIM, L_DIM);

    // z = leaky(leaky(xs@We1+be1)@We2+be2)  (fused, h stays on-chip)
    k_enc<<<MAXT, 256, 0, stream>>>(xs, Wt1, Wt2, be1, be2, zbuf, meta);
    // hd = leaky(z @ Wd1[e] + bd1[e])
    gemm_dec<E_DIM, H_DIM, true, false>
        <<<(H_DIM / 128) * MAXT, 256, 0, stream>>>(zbuf, Wd1t, bd1, hd, meta);
    // out = hd @ Wd2[e] + bd2[e]   (maps padded rows -> output rows)
    gemm_dec<H_DIM, L_DIM, false, true>
        <<<(L_DIM / 128) * MAXT, 256, 0, stream>>>(hd, Wd2t, bd2, out, meta);
}

// Round 4
// 222.414 us; speedup vs baseline: 1.5012x; 1.5012x over previous
//
#include <hip/hip_runtime.h>
#include <hip/hip_bf16.h>

#define B_ROWS 32768
#define L_DIM 512
#define H_DIM 1024
#define E_DIM 128
#define K_EXP 8
#define NBLK 128   // sort blocks: 32768/256

typedef __bf16 bf16x8 __attribute__((ext_vector_type(8)));
typedef float f32x4 __attribute__((ext_vector_type(4)));

__device__ __forceinline__ void gload16(const void* src, void* dst) {
    __builtin_amdgcn_global_load_lds(
        (const __attribute__((address_space(1))) unsigned int*)src,
        (__attribute__((address_space(3))) unsigned int*)dst, 16, 0, 0);
}

// ---------------- sort: ids + per-block histogram ----------------
__global__ void k_ids_hist(const float* __restrict__ x, int* __restrict__ ids,
                           int* __restrict__ hist) {
    __shared__ int lh[K_EXP];
    int t = threadIdx.x;
    if (t < K_EXP) lh[t] = 0;
    __syncthreads();
    int i = blockIdx.x * 256 + t;
    int id = (int)x[(size_t)i * (L_DIM + 1) + L_DIM];
    ids[i] = id;
    atomicAdd(&lh[id], 1);
    __syncthreads();
    if (t < K_EXP) hist[blockIdx.x * K_EXP + t] = lh[t];
}

__global__ void k_scan(const int* __restrict__ hist, int* __restrict__ base,
                       int* __restrict__ seg, int* __restrict__ tp) {
    __shared__ int c[K_EXP];
    __shared__ int sseg[K_EXP + 1];
    int k = threadIdx.x;
    if (k < K_EXP) {
        int run = 0;
        for (int b = 0; b < NBLK; ++b) {
            base[b * K_EXP + k] = run;
            run += hist[b * K_EXP + k];
        }
        c[k] = run;
    }
    __syncthreads();
    if (k == 0) {
        int s = 0, t2 = 0;
        for (int e = 0; e < K_EXP; ++e) {
            sseg[e] = s; seg[e] = s; tp[e] = t2;
            s += c[e]; t2 += (c[e] + 127) >> 7;
        }
        sseg[K_EXP] = s; seg[K_EXP] = s; tp[K_EXP] = t2;
    }
    __syncthreads();
    if (k < K_EXP) {
        int s0 = sseg[k];
        for (int b = 0; b < NBLK; ++b) base[b * K_EXP + k] += s0;
    }
}

__global__ void k_order(const int* __restrict__ ids, const int* __restrict__ base,
                        int* __restrict__ order) {
    __shared__ int sid[256];
    int t = threadIdx.x;
    int i = blockIdx.x * 256 + t;
    int my = ids[i];
    sid[t] = my;
    __syncthreads();
    int rank = 0;
    for (int j = 0; j < t; ++j) rank += (sid[j] == my) ? 1 : 0;
    order[base[blockIdx.x * K_EXP + my] + rank] = i;
}

__global__ void k_gather(const float* __restrict__ x, const int* __restrict__ order,
                         __hip_bfloat16* __restrict__ xs) {
    int idx = blockIdx.x * 256 + threadIdx.x;
    int p = idx >> 7;
    int c4 = (idx & 127) << 2;
    int src = order[p];
    const float* sp = x + (size_t)src * (L_DIM + 1) + c4;
    __hip_bfloat16 v[4];
    v[0] = __float2bfloat16(sp[0]);
    v[1] = __float2bfloat16(sp[1]);
    v[2] = __float2bfloat16(sp[2]);
    v[3] = __float2bfloat16(sp[3]);
    *(uint2*)(xs + (size_t)p * L_DIM + c4) = *(uint2*)v;
}

__global__ void k_transpose(const float* __restrict__ W, __hip_bfloat16* __restrict__ Wt,
                            int KDim, int NDim) {
    __shared__ float tile[32][33];
    int k0 = blockIdx.x << 5, n0 = blockIdx.y << 5;
    const float* Wb = W + (size_t)blockIdx.z * KDim * NDim;
    __hip_bfloat16* Wtb = Wt + (size_t)blockIdx.z * KDim * NDim;
    int tx = threadIdx.x & 31, ty = threadIdx.x >> 5;
    for (int i = ty; i < 32; i += 8)
        tile[i][tx] = Wb[(size_t)(k0 + i) * NDim + n0 + tx];
    __syncthreads();
    for (int i = ty; i < 32; i += 8)
        Wtb[(size_t)(n0 + i) * KDim + k0 + tx] = __float2bfloat16(tile[tx][i]);
}

// ---------------- ring-3 counted-vmcnt MFMA GEMM ----------------
// C[M,N] = epi(A[M,K] @ Bt[N,K]^T + bias); 128x128 tile, BK=32, 4 waves.
// 3 LDS buffers (48 KB -> 3 blocks/CU); stage tile t+2 while computing t;
// per-iter gate: s_waitcnt vmcnt(4) + s_barrier (never drains the pipe).
template <int KD, int ND, bool GROUPED, bool LEAKY, bool OUT_BF16>
__launch_bounds__(256)
__global__ void gemm_r3(const __hip_bfloat16* __restrict__ A,
                        const __hip_bfloat16* __restrict__ Bt,
                        const float* __restrict__ bias,
                        void* __restrict__ Cout,
                        const int* __restrict__ seg, const int* __restrict__ tp) {
    __shared__ __align__(16) __hip_bfloat16 smem[3 * 2 * 128 * 32];  // 48 KB
    const int t = threadIdx.x;
    const int w = t >> 6, l = t & 63;
    const int n0 = blockIdx.y << 7;
    int m0, mEnd;
    const __hip_bfloat16* Bp = Bt;
    const float* bp = bias;
    if (GROUPED) {
        int bx = blockIdx.x;
        if (bx >= tp[K_EXP]) return;
        int e = 0;
        while (bx >= tp[e + 1]) ++e;
        m0 = seg[e] + ((bx - tp[e]) << 7);
        mEnd = seg[e + 1];
        Bp += (size_t)e * KD * ND;
        bp += (size_t)e * ND;
    } else {
        m0 = blockIdx.x << 7;
        mEnd = m0 + 128;
    }
    const int wm = w >> 1, wn = w & 1, g = l >> 4, li = l & 15;
    const int q0 = 2 * w, r0 = l >> 2, s0 = l & 3;

    f32x4 acc[4][4];
#pragma unroll
    for (int i = 0; i < 4; ++i)
#pragma unroll
        for (int j = 0; j < 4; ++j) acc[i][j] = (f32x4){0.f, 0.f, 0.f, 0.f};

    // stage K-tile kt into ring buffer b (4 gload_lds per thread: 2 A + 2 B)
    auto stage = [&](int b, int kt) {
#pragma unroll
        for (int qi = 0; qi < 2; ++qi) {
            int q = q0 + qi, r = q * 16 + r0;
            int ksg = s0 ^ ((r >> 1) & 3);
            int rowg = m0 + r;
            if (GROUPED) rowg = min(rowg, B_ROWS - 1);
            gload16(A + (size_t)rowg * KD + kt * 32 + ksg * 8,
                    &smem[b * 8192 + q * 512]);
        }
#pragma unroll
        for (int qi = 0; qi < 2; ++qi) {
            int q = q0 + qi, r = q * 16 + r0;
            int ksg = s0 ^ ((r >> 1) & 3);
            gload16(Bp + (size_t)(n0 + r) * KD + kt * 32 + ksg * 8,
                    &smem[b * 8192 + 4096 + q * 512]);
        }
    };

    constexpr int NK = KD / 32;
    stage(0, 0);
    stage(1, 1);
    int b = 0;
    for (int kt = 0; kt < NK; ++kt) {
        // gate: tile kt's loads landed (leave the newer 4 in flight), then barrier
        if (kt == NK - 1)
            asm volatile("s_waitcnt vmcnt(0)\ns_barrier" ::: "memory");
        else
            asm volatile("s_waitcnt vmcnt(4)\ns_barrier" ::: "memory");
        __builtin_amdgcn_sched_barrier(0);
        if (kt + 2 < NK) stage((b + 2 >= 3) ? b - 1 : b + 2, kt + 2);
        bf16x8 af[4], bfr[4];
#pragma unroll
        for (int fm = 0; fm < 4; ++fm) {
            int rr = wm * 64 + fm * 16 + li;
            int ss = g ^ ((rr >> 1) & 3);
            af[fm] = *(const bf16x8*)&smem[b * 8192 + rr * 32 + ss * 8];
        }
#pragma unroll
        for (int fn = 0; fn < 4; ++fn) {
            int cc = wn * 64 + fn * 16 + li;
            int ss = g ^ ((cc >> 1) & 3);
            bfr[fn] = *(const bf16x8*)&smem[b * 8192 + 4096 + cc * 32 + ss * 8];
        }
        __builtin_amdgcn_s_setprio(1);
#pragma unroll
        for (int fm = 0; fm < 4; ++fm)
#pragma unroll
            for (int fn = 0; fn < 4; ++fn)
                acc[fm][fn] = __builtin_amdgcn_mfma_f32_16x16x32_bf16(
                    af[fm], bfr[fn], acc[fm][fn], 0, 0, 0);
        __builtin_amdgcn_s_setprio(0);
        b = (b + 1 >= 3) ? 0 : b + 1;
    }

    float bv[4];
#pragma unroll
    for (int fn = 0; fn < 4; ++fn) bv[fn] = bp[n0 + wn * 64 + fn * 16 + li];
#pragma unroll
    for (int fm = 0; fm < 4; ++fm)
#pragma unroll
        for (int i = 0; i < 4; ++i) {
            int r = m0 + wm * 64 + fm * 16 + g * 4 + i;
            if (!GROUPED || r < mEnd) {
#pragma unroll
                for (int fn = 0; fn < 4; ++fn) {
                    float v = acc[fm][fn][i] + bv[fn];
                    if (LEAKY) v = v > 0.f ? v : 0.01f * v;
                    size_t off = (size_t)r * ND + n0 + wn * 64 + fn * 16 + li;
                    if (OUT_BF16)
                        ((__hip_bfloat16*)Cout)[off] = __float2bfloat16(v);
                    else
                        ((float*)Cout)[off] = v;
                }
            }
        }
}

// ---------------- R2's proven 2-buffer kernel (kept for G3, K=128) ----------------
template <int KD, int ND, bool GROUPED, bool LEAKY, bool OUT_BF16>
__launch_bounds__(256)
__global__ void gemm_mfma(const __hip_bfloat16* __restrict__ A,
                          const __hip_bfloat16* __restrict__ Bt,
                          const float* __restrict__ bias,
                          void* __restrict__ Cout,
                          const int* __restrict__ seg, const int* __restrict__ tp) {
    __shared__ __align__(16) __hip_bfloat16 smem[2 * 2 * 128 * 32];
    const int t = threadIdx.x;
    const int w = t >> 6, l = t & 63;
    const int n0 = blockIdx.y << 7;
    int m0, mEnd;
    const __hip_bfloat16* Bp = Bt;
    const float* bp = bias;
    if (GROUPED) {
        int bx = blockIdx.x;
        if (bx >= tp[K_EXP]) return;
        int e = 0;
        while (bx >= tp[e + 1]) ++e;
        m0 = seg[e] + ((bx - tp[e]) << 7);
        mEnd = seg[e + 1];
        Bp += (size_t)e * KD * ND;
        bp += (size_t)e * ND;
    } else {
        m0 = blockIdx.x << 7;
        mEnd = m0 + 128;
    }
    const int wm = w >> 1, wn = w & 1, g = l >> 4, li = l & 15;
    const int q0 = 2 * w, r0 = l >> 2, s0 = l & 3;

    f32x4 acc[4][4];
#pragma unroll
    for (int i = 0; i < 4; ++i)
#pragma unroll
        for (int j = 0; j < 4; ++j) acc[i][j] = (f32x4){0.f, 0.f, 0.f, 0.f};

    auto stage = [&](int buf, int kt) {
#pragma unroll
        for (int qi = 0; qi < 2; ++qi) {
            int q = q0 + qi, r = q * 16 + r0;
            int ksg = s0 ^ ((r >> 1) & 3);
            int rowg = m0 + r;
            if (GROUPED) rowg = min(rowg, B_ROWS - 1);
            gload16(A + (size_t)rowg * KD + kt * 32 + ksg * 8,
                    &smem[(buf * 2 + 0) * 4096 + q * 512]);
        }
#pragma unroll
        for (int qi = 0; qi < 2; ++qi) {
            int q = q0 + qi, r = q * 16 + r0;
            int ksg = s0 ^ ((r >> 1) & 3);
            gload16(Bp + (size_t)(n0 + r) * KD + kt * 32 + ksg * 8,
                    &smem[(buf * 2 + 1) * 4096 + q * 512]);
        }
    };

    constexpr int NK = KD / 32;
    stage(0, 0);
    for (int kt = 0; kt < NK; ++kt) {
        int buf = kt & 1;
        __syncthreads();
        if (kt + 1 < NK) stage(buf ^ 1, kt + 1);
        bf16x8 af[4], bfr[4];
#pragma unroll
        for (int fm = 0; fm < 4; ++fm) {
            int rr = wm * 64 + fm * 16 + li;
            int ss = g ^ ((rr >> 1) & 3);
            af[fm] = *(const bf16x8*)&smem[(buf * 2 + 0) * 4096 + rr * 32 + ss * 8];
        }
#pragma unroll
        for (int fn = 0; fn < 4; ++fn) {
            int cc = wn * 64 + fn * 16 + li;
            int ss = g ^ ((cc >> 1) & 3);
            bfr[fn] = *(const bf16x8*)&smem[(buf * 2 + 1) * 4096 + cc * 32 + ss * 8];
        }
#pragma unroll
        for (int fm = 0; fm < 4; ++fm)
#pragma unroll
            for (int fn = 0; fn < 4; ++fn)
                acc[fm][fn] = __builtin_amdgcn_mfma_f32_16x16x32_bf16(
                    af[fm], bfr[fn], acc[fm][fn], 0, 0, 0);
    }

    float bv[4];
#pragma unroll
    for (int fn = 0; fn < 4; ++fn) bv[fn] = bp[n0 + wn * 64 + fn * 16 + li];
#pragma unroll
    for (int fm = 0; fm < 4; ++fm)
#pragma unroll
        for (int i = 0; i < 4; ++i) {
            int r = m0 + wm * 64 + fm * 16 + g * 4 + i;
            if (!GROUPED || r < mEnd) {
#pragma unroll
                for (int fn = 0; fn < 4; ++fn) {
                    float v = acc[fm][fn][i] + bv[fn];
                    if (LEAKY) v = v > 0.f ? v : 0.01f * v;
                    size_t off = (size_t)r * ND + n0 + wn * 64 + fn * 16 + li;
                    if (OUT_BF16)
                        ((__hip_bfloat16*)Cout)[off] = __float2bfloat16(v);
                    else
                        ((float*)Cout)[off] = v;
                }
            }
        }
}

extern "C" void kernel_launch(void* const* d_in, const int* in_sizes, int n_in,
                              void* d_out, int out_size, void* d_ws, size_t ws_size,
                              hipStream_t stream) {
    (void)in_sizes; (void)n_in; (void)out_size; (void)ws_size;
    const float* x   = (const float*)d_in[0];
    const float* We1 = (const float*)d_in[1];
    const float* be1 = (const float*)d_in[2];
    const float* We2 = (const float*)d_in[3];
    const float* be2 = (const float*)d_in[4];
    const float* Wd1 = (const float*)d_in[5];
    const float* bd1 = (const float*)d_in[6];
    const float* Wd2 = (const float*)d_in[7];
    const float* bd2 = (const float*)d_in[8];
    float* out = (float*)d_out;

    char* w = (char*)d_ws;
    auto alloc = [&](size_t bytes) {
        char* p = w;
        w += (bytes + 255) & ~(size_t)255;
        return p;
    };
    int* ids   = (int*)alloc((size_t)B_ROWS * 4);
    int* order = (int*)alloc((size_t)B_ROWS * 4);
    int* hist  = (int*)alloc((size_t)NBLK * K_EXP * 4);
    int* base  = (int*)alloc((size_t)NBLK * K_EXP * 4);
    int* seg   = (int*)alloc((K_EXP + 1) * 4);
    int* tp    = (int*)alloc((K_EXP + 1) * 4);
    __hip_bfloat16* xs   = (__hip_bfloat16*)alloc((size_t)B_ROWS * L_DIM * 2);
    __hip_bfloat16* hbuf = (__hip_bfloat16*)alloc((size_t)B_ROWS * H_DIM * 2);
    __hip_bfloat16* zbuf = (__hip_bfloat16*)alloc((size_t)B_ROWS * E_DIM * 2);
    __hip_bfloat16* Wt1  = (__hip_bfloat16*)alloc((size_t)L_DIM * H_DIM * 2);
    __hip_bfloat16* Wt2  = (__hip_bfloat16*)alloc((size_t)H_DIM * E_DIM * 2);
    __hip_bfloat16* Wd1t = (__hip_bfloat16*)alloc((size_t)K_EXP * E_DIM * H_DIM * 2);
    __hip_bfloat16* Wd2t = (__hip_bfloat16*)alloc((size_t)K_EXP * H_DIM * L_DIM * 2);

    k_ids_hist<<<NBLK, 256, 0, stream>>>(x, ids, hist);
    k_scan<<<1, 64, 0, stream>>>(hist, base, seg, tp);
    k_order<<<NBLK, 256, 0, stream>>>(ids, base, order);
    k_gather<<<(B_ROWS * (L_DIM / 4)) / 256, 256, 0, stream>>>(x, order, xs);

    k_transpose<<<dim3(L_DIM / 32, H_DIM / 32, 1), 256, 0, stream>>>(We1, Wt1, L_DIM, H_DIM);
    k_transpose<<<dim3(H_DIM / 32, E_DIM / 32, 1), 256, 0, stream>>>(We2, Wt2, H_DIM, E_DIM);
    k_transpose<<<dim3(E_DIM / 32, H_DIM / 32, K_EXP), 256, 0, stream>>>(Wd1, Wd1t, E_DIM, H_DIM);
    k_transpose<<<dim3(H_DIM / 32, L_DIM / 32, K_EXP), 256, 0, stream>>>(Wd2, Wd2t, H_DIM, L_DIM);

    // h = leaky(xs @ We1 + be1)            (ring-3)
    gemm_r3<L_DIM, H_DIM, false, true, true>
        <<<dim3(B_ROWS / 128, H_DIM / 128), 256, 0, stream>>>(xs, Wt1, be1, hbuf, nullptr, nullptr);
    // z = leaky(h @ We2 + be2)             (ring-3; deep prefetch for 1-block/CU shape)
    gemm_r3<H_DIM, E_DIM, false, true, true>
        <<<dim3(B_ROWS / 128, E_DIM / 128), 256, 0, stream>>>(hbuf, Wt2, be2, zbuf, nullptr, nullptr);
    // hd = leaky(z @ Wd1[e] + bd1[e])      (grouped, R2 kernel as control)
    gemm_mfma<E_DIM, H_DIM, true, true, true>
        <<<dim3(B_ROWS / 128 + K_EXP, H_DIM / 128), 256, 0, stream>>>(zbuf, Wd1t, bd1, hbuf, seg, tp);
    // out = hd @ Wd2[e] + bd2[e]           (grouped ring-3, fp32 out)
    gemm_r3<H_DIM, L_DIM, true, false, false>
        <<<dim3(B_ROWS / 128 + K_EXP, L_DIM / 128), 256, 0, stream>>>(hbuf, Wd2t, bd2, out, seg, tp);
}

// Round 5
// 208.561 us; speedup vs baseline: 1.6009x; 1.0664x over previous
//
#include <hip/hip_runtime.h>
#include <hip/hip_bf16.h>

#define B_ROWS 32768
#define L_DIM 512
#define H_DIM 1024
#define E_DIM 128
#define K_EXP 8
#define NBLK 128   // sort blocks: 32768/256

typedef __bf16 bf16x8 __attribute__((ext_vector_type(8)));
typedef float f32x4 __attribute__((ext_vector_type(4)));

__device__ __forceinline__ void gload16(const void* src, void* dst) {
    __builtin_amdgcn_global_load_lds(
        (const __attribute__((address_space(1))) unsigned int*)src,
        (__attribute__((address_space(3))) unsigned int*)dst, 16, 0, 0);
}

// ---------------- sort: ids + per-block histogram ----------------
__global__ void k_ids_hist(const float* __restrict__ x, int* __restrict__ ids,
                           int* __restrict__ hist) {
    __shared__ int lh[K_EXP];
    int t = threadIdx.x;
    if (t < K_EXP) lh[t] = 0;
    __syncthreads();
    int i = blockIdx.x * 256 + t;
    int id = (int)x[(size_t)i * (L_DIM + 1) + L_DIM];
    ids[i] = id;
    atomicAdd(&lh[id], 1);
    __syncthreads();
    if (t < K_EXP) hist[blockIdx.x * K_EXP + t] = lh[t];
}

__global__ void k_scan(const int* __restrict__ hist, int* __restrict__ base,
                       int* __restrict__ seg, int* __restrict__ tp) {
    __shared__ int c[K_EXP];
    __shared__ int sseg[K_EXP + 1];
    int k = threadIdx.x;
    if (k < K_EXP) {
        int run = 0;
        for (int b = 0; b < NBLK; ++b) {
            base[b * K_EXP + k] = run;
            run += hist[b * K_EXP + k];
        }
        c[k] = run;
    }
    __syncthreads();
    if (k == 0) {
        int s = 0, t2 = 0;
        for (int e = 0; e < K_EXP; ++e) {
            sseg[e] = s; seg[e] = s; tp[e] = t2;
            s += c[e]; t2 += (c[e] + 127) >> 7;
        }
        sseg[K_EXP] = s; seg[K_EXP] = s; tp[K_EXP] = t2;
    }
    __syncthreads();
    if (k < K_EXP) {
        int s0 = sseg[k];
        for (int b = 0; b < NBLK; ++b) base[b * K_EXP + k] += s0;
    }
}

__global__ void k_order(const int* __restrict__ ids, const int* __restrict__ base,
                        int* __restrict__ order) {
    __shared__ int sid[256];
    int t = threadIdx.x;
    int i = blockIdx.x * 256 + t;
    int my = ids[i];
    sid[t] = my;
    __syncthreads();
    int rank = 0;
    for (int j = 0; j < t; ++j) rank += (sid[j] == my) ? 1 : 0;
    order[base[blockIdx.x * K_EXP + my] + rank] = i;
}

__global__ void k_gather(const float* __restrict__ x, const int* __restrict__ order,
                         __hip_bfloat16* __restrict__ xs) {
    int idx = blockIdx.x * 256 + threadIdx.x;
    int p = idx >> 7;
    int c4 = (idx & 127) << 2;
    int src = order[p];
    const float* sp = x + (size_t)src * (L_DIM + 1) + c4;
    __hip_bfloat16 v[4];
    v[0] = __float2bfloat16(sp[0]);
    v[1] = __float2bfloat16(sp[1]);
    v[2] = __float2bfloat16(sp[2]);
    v[3] = __float2bfloat16(sp[3]);
    *(uint2*)(xs + (size_t)p * L_DIM + c4) = *(uint2*)v;
}

__global__ void k_transpose(const float* __restrict__ W, __hip_bfloat16* __restrict__ Wt,
                            int KDim, int NDim) {
    __shared__ float tile[32][33];
    int k0 = blockIdx.x << 5, n0 = blockIdx.y << 5;
    const float* Wb = W + (size_t)blockIdx.z * KDim * NDim;
    __hip_bfloat16* Wtb = Wt + (size_t)blockIdx.z * KDim * NDim;
    int tx = threadIdx.x & 31, ty = threadIdx.x >> 5;
    for (int i = ty; i < 32; i += 8)
        tile[i][tx] = Wb[(size_t)(k0 + i) * NDim + n0 + tx];
    __syncthreads();
    for (int i = ty; i < 32; i += 8)
        Wtb[(size_t)(n0 + i) * KDim + k0 + tx] = __float2bfloat16(tile[tx][i]);
}

// ---------------- unified ring-3 MFMA GEMM ----------------
// C[M,N] = epi(A[M,KD] @ Bt[N,KD]^T + bias); BM x 128 tile, BK=32, 4 waves.
// 1D grid, n-fastest decode + bijective XCD chunking (same-XCD blocks share
// the A-panel -> L2 hits; B panel L2-resident). 3 LDS ring slots; stage tile
// t+2 while computing t; gate s_waitcnt vmcnt(loads-per-stage) + s_barrier.
template <int BM, int KD, int ND, bool GROUPED, bool LEAKY, bool OUT_BF16>
__launch_bounds__(256)
__global__ void gemm_u(const __hip_bfloat16* __restrict__ A,
                       const __hip_bfloat16* __restrict__ Bt,
                       const float* __restrict__ bias,
                       void* __restrict__ Cout,
                       const int* __restrict__ seg, const int* __restrict__ tp) {
    static_assert(!GROUPED || BM == 128, "grouped tiles are 128 rows");
    constexpr int NNT = ND / 128;
    constexpr int NMT = GROUPED ? (B_ROWS / 128 + K_EXP) : (B_ROWS / BM);
    constexpr int TOT = NMT * NNT;
    static_assert(TOT % 8 == 0, "XCD chunking needs TOT % 8 == 0");
    constexpr int ACH = BM * 32;          // A elems per ring slot
    constexpr int SLOT = ACH + 128 * 32;  // elems per ring slot (A + B)
    constexpr int NK = KD / 32;
    constexpr int VG = (BM == 128) ? 4 : 3;  // gloads per stage()

    __shared__ __align__(16) __hip_bfloat16 smem[3 * SLOT];
    const int id = blockIdx.x;
    const int wg = (id & 7) * (TOT / 8) + (id >> 3);
    const int mt = wg / NNT, nt = wg % NNT;
    const int n0 = nt << 7;
    int m0, mEnd;
    const __hip_bfloat16* Bp = Bt;
    const float* bp = bias;
    if (GROUPED) {
        if (mt >= tp[K_EXP]) return;
        int e = 0;
        while (mt >= tp[e + 1]) ++e;
        m0 = seg[e] + ((mt - tp[e]) << 7);
        mEnd = seg[e + 1];
        Bp += (size_t)e * KD * ND;
        bp += (size_t)e * ND;
    } else {
        m0 = mt * BM;
        mEnd = m0 + BM;
    }
    const int t = threadIdx.x, w = t >> 6, l = t & 63;
    constexpr int FM = BM / 32;           // 16-row frags per wave (m)
    const int wm = w >> 1, wn = w & 1, g = l >> 4, li = l & 15;
    const int r0 = l >> 2, s0 = l & 3;

    f32x4 acc[FM][4];
#pragma unroll
    for (int i = 0; i < FM; ++i)
#pragma unroll
        for (int j = 0; j < 4; ++j) acc[i][j] = (f32x4){0.f, 0.f, 0.f, 0.f};

    auto stage = [&](int b, int kt) {
#pragma unroll
        for (int qi = 0; qi < BM / 64; ++qi) {     // A: BM/16 chunks over 4 waves
            int q = (BM / 64) * w + qi;
            int r = q * 16 + r0;
            int ksg = s0 ^ ((r >> 1) & 3);
            int rowg = m0 + r;
            if (GROUPED) rowg = min(rowg, B_ROWS - 1);
            gload16(A + (size_t)rowg * KD + kt * 32 + ksg * 8,
                    &smem[b * SLOT + q * 512]);
        }
#pragma unroll
        for (int qi = 0; qi < 2; ++qi) {           // B: 8 chunks over 4 waves
            int q = 2 * w + qi;
            int r = q * 16 + r0;
            int ksg = s0 ^ ((r >> 1) & 3);
            gload16(Bp + (size_t)(n0 + r) * KD + kt * 32 + ksg * 8,
                    &smem[b * SLOT + ACH + q * 512]);
        }
    };

    stage(0, 0);
    stage(1, 1);
    int b = 0;
    for (int kt = 0; kt < NK; ++kt) {
        if (kt == NK - 1)
            asm volatile("s_waitcnt vmcnt(0)\ns_barrier" ::: "memory");
        else if constexpr (VG == 4)
            asm volatile("s_waitcnt vmcnt(4)\ns_barrier" ::: "memory");
        else
            asm volatile("s_waitcnt vmcnt(3)\ns_barrier" ::: "memory");
        __builtin_amdgcn_sched_barrier(0);
        if (kt + 2 < NK) stage((b + 2 >= 3) ? b - 1 : b + 2, kt + 2);
        bf16x8 af[FM], bfr[4];
#pragma unroll
        for (int fm = 0; fm < FM; ++fm) {
            int rr = wm * (FM * 16) + fm * 16 + li;
            int ss = g ^ ((rr >> 1) & 3);
            af[fm] = *(const bf16x8*)&smem[b * SLOT + rr * 32 + ss * 8];
        }
#pragma unroll
        for (int fn = 0; fn < 4; ++fn) {
            int cc = wn * 64 + fn * 16 + li;
            int ss = g ^ ((cc >> 1) & 3);
            bfr[fn] = *(const bf16x8*)&smem[b * SLOT + ACH + cc * 32 + ss * 8];
        }
        __builtin_amdgcn_s_setprio(1);
#pragma unroll
        for (int fm = 0; fm < FM; ++fm)
#pragma unroll
            for (int fn = 0; fn < 4; ++fn)
                acc[fm][fn] = __builtin_amdgcn_mfma_f32_16x16x32_bf16(
                    af[fm], bfr[fn], acc[fm][fn], 0, 0, 0);
        __builtin_amdgcn_s_setprio(0);
        b = (b + 1 >= 3) ? 0 : b + 1;
    }

    float bv[4];
#pragma unroll
    for (int fn = 0; fn < 4; ++fn) bv[fn] = bp[n0 + wn * 64 + fn * 16 + li];
#pragma unroll
    for (int fm = 0; fm < FM; ++fm)
#pragma unroll
        for (int i = 0; i < 4; ++i) {
            int r = m0 + wm * (FM * 16) + fm * 16 + g * 4 + i;
            if (!GROUPED || r < mEnd) {
#pragma unroll
                for (int fn = 0; fn < 4; ++fn) {
                    float v = acc[fm][fn][i] + bv[fn];
                    if (LEAKY) v = v > 0.f ? v : 0.01f * v;
                    size_t off = (size_t)r * ND + n0 + wn * 64 + fn * 16 + li;
                    if (OUT_BF16)
                        ((__hip_bfloat16*)Cout)[off] = __float2bfloat16(v);
                    else
                        ((float*)Cout)[off] = v;
                }
            }
        }
}

extern "C" void kernel_launch(void* const* d_in, const int* in_sizes, int n_in,
                              void* d_out, int out_size, void* d_ws, size_t ws_size,
                              hipStream_t stream) {
    (void)in_sizes; (void)n_in; (void)out_size; (void)ws_size;
    const float* x   = (const float*)d_in[0];
    const float* We1 = (const float*)d_in[1];
    const float* be1 = (const float*)d_in[2];
    const float* We2 = (const float*)d_in[3];
    const float* be2 = (const float*)d_in[4];
    const float* Wd1 = (const float*)d_in[5];
    const float* bd1 = (const float*)d_in[6];
    const float* Wd2 = (const float*)d_in[7];
    const float* bd2 = (const float*)d_in[8];
    float* out = (float*)d_out;

    char* w = (char*)d_ws;
    auto alloc = [&](size_t bytes) {
        char* p = w;
        w += (bytes + 255) & ~(size_t)255;
        return p;
    };
    int* ids   = (int*)alloc((size_t)B_ROWS * 4);
    int* order = (int*)alloc((size_t)B_ROWS * 4);
    int* hist  = (int*)alloc((size_t)NBLK * K_EXP * 4);
    int* base  = (int*)alloc((size_t)NBLK * K_EXP * 4);
    int* seg   = (int*)alloc((K_EXP + 1) * 4);
    int* tp    = (int*)alloc((K_EXP + 1) * 4);
    __hip_bfloat16* xs   = (__hip_bfloat16*)alloc((size_t)B_ROWS * L_DIM * 2);
    __hip_bfloat16* hbuf = (__hip_bfloat16*)alloc((size_t)B_ROWS * H_DIM * 2);
    __hip_bfloat16* zbuf = (__hip_bfloat16*)alloc((size_t)B_ROWS * E_DIM * 2);
    __hip_bfloat16* Wt1  = (__hip_bfloat16*)alloc((size_t)L_DIM * H_DIM * 2);
    __hip_bfloat16* Wt2  = (__hip_bfloat16*)alloc((size_t)H_DIM * E_DIM * 2);
    __hip_bfloat16* Wd1t = (__hip_bfloat16*)alloc((size_t)K_EXP * E_DIM * H_DIM * 2);
    __hip_bfloat16* Wd2t = (__hip_bfloat16*)alloc((size_t)K_EXP * H_DIM * L_DIM * 2);

    k_ids_hist<<<NBLK, 256, 0, stream>>>(x, ids, hist);
    k_scan<<<1, 64, 0, stream>>>(hist, base, seg, tp);
    k_order<<<NBLK, 256, 0, stream>>>(ids, base, order);
    k_gather<<<(B_ROWS * (L_DIM / 4)) / 256, 256, 0, stream>>>(x, order, xs);

    k_transpose<<<dim3(L_DIM / 32, H_DIM / 32, 1), 256, 0, stream>>>(We1, Wt1, L_DIM, H_DIM);
    k_transpose<<<dim3(H_DIM / 32, E_DIM / 32, 1), 256, 0, stream>>>(We2, Wt2, H_DIM, E_DIM);
    k_transpose<<<dim3(E_DIM / 32, H_DIM / 32, K_EXP), 256, 0, stream>>>(Wd1, Wd1t, E_DIM, H_DIM);
    k_transpose<<<dim3(H_DIM / 32, L_DIM / 32, K_EXP), 256, 0, stream>>>(Wd2, Wd2t, H_DIM, L_DIM);

    // h = leaky(xs @ We1 + be1)        [32768,512]@[512,1024]
    gemm_u<128, L_DIM, H_DIM, false, true, true>
        <<<(B_ROWS / 128) * (H_DIM / 128), 256, 0, stream>>>(xs, Wt1, be1, hbuf, nullptr, nullptr);
    // z = leaky(h @ We2 + be2)         [32768,1024]@[1024,128]  (BM=64 -> 512 blocks)
    gemm_u<64, H_DIM, E_DIM, false, true, true>
        <<<(B_ROWS / 64) * (E_DIM / 128), 256, 0, stream>>>(hbuf, Wt2, be2, zbuf, nullptr, nullptr);
    // hd = leaky(z @ Wd1[e] + bd1[e])  grouped
    gemm_u<128, E_DIM, H_DIM, true, true, true>
        <<<(B_ROWS / 128 + K_EXP) * (H_DIM / 128), 256, 0, stream>>>(zbuf, Wd1t, bd1, hbuf, seg, tp);
    // out = hd @ Wd2[e] + bd2[e]       grouped, fp32 out
    gemm_u<128, H_DIM, L_DIM, true, false, false>
        <<<(B_ROWS / 128 + K_EXP) * (L_DIM / 128), 256, 0, stream>>>(hbuf, Wd2t, bd2, out, seg, tp);
}